// Round 12
// baseline (196.741 us; speedup 1.0000x reference)
//
#include <hip/hip_runtime.h>
#include <hip/hip_bf16.h>

#define T_TOK 4096
#define D_IN  2048
#define HS    128
#define CKV   4      // KV tiles per attention chunk
#define NCH   16     // ceil(64 / CKV)

typedef unsigned short u16;
typedef __attribute__((ext_vector_type(8))) __bf16 bf16x8;
typedef __attribute__((ext_vector_type(4))) float f32x4;
typedef __attribute__((ext_vector_type(4))) unsigned short us4;
typedef __attribute__((ext_vector_type(8))) unsigned short us8;

#define GLOBAL_AS __attribute__((address_space(1)))
#define LDS_AS    __attribute__((address_space(3)))

__device__ __forceinline__ void async_ld16(const void* g, void* l) {
  __builtin_amdgcn_global_load_lds((GLOBAL_AS void*)(void*)g, (LDS_AS void*)l, 16, 0, 0);
}

__device__ __forceinline__ u16 f2bf(float v) {
  return __builtin_bit_cast(u16, __float2bfloat16(v));
}

// ---------------------------------------------------------------------------
// fp32-vs-bf16 autodetect on a buffer head: even u16s of fp32 data are raw
// low-mantissa bits -> ~25% have "exponent" field >= 0xBF; genuine bf16
// N(0,s) has none. Returns wave-uniform flag via LDS broadcast.
// ---------------------------------------------------------------------------
__device__ __forceinline__ bool detect_f32(const u16* in, int tid, int* sflag) {
  if (tid < 64) {
    int cnt = 0;
#pragma unroll
    for (int j = 0; j < 8; j++) {
      u16 v = in[(tid * 8 + j) * 2];
      cnt += (((v >> 7) & 0xFF) >= 0xBF) ? 1 : 0;
    }
#pragma unroll
    for (int off = 1; off < 64; off <<= 1) cnt += __shfl_xor(cnt, off);
    if (tid == 0) *sflag = (cnt > 8) ? 1 : 0;
  }
  __syncthreads();
  return (*sflag != 0);
}

// ---------------------------------------------------------------------------
// Weight normalizer: all three matrices, 128 blocks each; converts fp32->bf16
// (or copies bf16). mat0/blk0 publishes the dtype flag for the epilogue.
// ---------------------------------------------------------------------------
__global__ __launch_bounds__(256) void conv3_kernel(
    const u16* __restrict__ w0, const u16* __restrict__ w1,
    const u16* __restrict__ w2, u16* __restrict__ o0,
    u16* __restrict__ o1, u16* __restrict__ o2, int* __restrict__ flag) {
  __shared__ int sflag;
  const int mat = blockIdx.x >> 7;
  const int blk = blockIdx.x & 127;
  const u16* in = (mat == 0) ? w0 : ((mat == 1) ? w1 : w2);
  u16* out = (mat == 0) ? o0 : ((mat == 1) ? o1 : o2);
  const int tid = threadIdx.x;
  const bool isf32 = detect_f32(in, tid, &sflag);
  if (tid == 0 && mat == 0 && blk == 0) *flag = isf32 ? 1 : 0;
  const size_t base = ((size_t)blk * 256 + tid) * 8;
  if (isf32) {
    const float* f = (const float*)in;
    us4 a, b;
#pragma unroll
    for (int j = 0; j < 4; j++) a[j] = f2bf(f[base + j]);
#pragma unroll
    for (int j = 0; j < 4; j++) b[j] = f2bf(f[base + 4 + j]);
    *(us4*)(out + base) = a;
    *(us4*)(out + base + 4) = b;
  } else {
    *(us8*)(out + base) = *(const us8*)(in + base);
  }
}

// ---------------------------------------------------------------------------
// QKV projection v5: barrier-free wave-autonomous GEMM, depth-2 register
// pipeline (AITER pattern: loads for kt+2 in flight while computing kt;
// waitcnt never forced to 0 — no __syncthreads in the K-loop at all).
// Round-11 lesson: v4's in-iteration B loads (no look-ahead) exposed L2
// latency serially; the staged variants are capped by the barrier's
// vmcnt(0) drain (one iteration of staging in flight max). v5 removes both.
// grid (128 m-tiles, 3 mats), 256 thr; wave = 16 rows x 64 cols:
// rb=wv&1 (row band), ch=wv>>1 (col half). BK=32, 64 steps.
// x redundancy 2x (2nd read L3-hit); W bf16 is L2-resident.
// ---------------------------------------------------------------------------
__global__ __launch_bounds__(256, 2) void qkv_kernel(
    const u16* __restrict__ x, const u16* __restrict__ Wq,
    const u16* __restrict__ Wk, const u16* __restrict__ Wv,
    u16* __restrict__ Q, u16* __restrict__ K, u16* __restrict__ Vt)
{
  __shared__ int sflag;
  const int mat = blockIdx.y;
  const u16* W = (mat == 0) ? Wq : ((mat == 1) ? Wk : Wv);
  const int tid = threadIdx.x;
  const int wv = tid >> 6, lane = tid & 63, l15 = lane & 15, quad = lane >> 4;
  const int rb = wv & 1, ch = wv >> 1;
  const int row0 = (int)blockIdx.x * 32;
  const bool isf32 = detect_f32(x, tid, &sflag);

  const int myrow = row0 + 16 * rb + l15;
  const float* xf = (const float*)x + (size_t)myrow * D_IN + quad * 8;
  const u16*  xh = x + (size_t)myrow * D_IN + quad * 8;
  const u16* Wr0 = W + (size_t)(64 * ch + l15) * D_IN + quad * 8;
  const u16* Wr1 = Wr0 + (size_t)16 * D_IN;
  const u16* Wr2 = Wr0 + (size_t)32 * D_IN;
  const u16* Wr3 = Wr0 + (size_t)48 * D_IN;

  f32x4 acc[4];
#pragma unroll
  for (int i = 0; i < 4; i++) acc[i] = (f32x4)0.0f;

  // depth-2 register pipeline buffers
  f32x4 pa[2][2];       // fp32 A halves
  bf16x8 pab[2];        // bf16 A
  bf16x8 pb[2][4];      // B frags

  auto pf = [&](int kt, int sl) {
    const int k0 = kt * 32;
    if (isf32) {
      pa[sl][0] = *(const f32x4*)(xf + k0);
      pa[sl][1] = *(const f32x4*)(xf + k0 + 4);
    } else {
      pab[sl] = *(const bf16x8*)(xh + k0);
    }
    pb[sl][0] = *(const bf16x8*)(Wr0 + k0);
    pb[sl][1] = *(const bf16x8*)(Wr1 + k0);
    pb[sl][2] = *(const bf16x8*)(Wr2 + k0);
    pb[sl][3] = *(const bf16x8*)(Wr3 + k0);
  };

  pf(0, 0);
  pf(1, 1);

#pragma unroll 2
  for (int kt = 0; kt < 64; kt++) {
    const int sl = kt & 1;
    // pull current slot into locals before overwriting it with the prefetch
    bf16x8 a;
    if (isf32) {
      us8 t;
#pragma unroll
      for (int j = 0; j < 4; j++) { t[j] = f2bf(pa[sl][0][j]); t[4 + j] = f2bf(pa[sl][1][j]); }
      a = __builtin_bit_cast(bf16x8, t);
    } else {
      a = pab[sl];
    }
    bf16x8 b0 = pb[sl][0], b1 = pb[sl][1], b2 = pb[sl][2], b3 = pb[sl][3];
    if (kt + 2 < 64) pf(kt + 2, sl);
    acc[0] = __builtin_amdgcn_mfma_f32_16x16x32_bf16(a, b0, acc[0], 0, 0, 0);
    acc[1] = __builtin_amdgcn_mfma_f32_16x16x32_bf16(a, b1, acc[1], 0, 0, 0);
    acc[2] = __builtin_amdgcn_mfma_f32_16x16x32_bf16(a, b2, acc[2], 0, 0, 0);
    acc[3] = __builtin_amdgcn_mfma_f32_16x16x32_bf16(a, b3, acc[3], 0, 0, 0);
  }

  // epilogue. D-frag: row = quad*4 + r, col = 16*nt + l15 (within wave tile)
  if (mat < 2) {
    u16* out = (mat == 0) ? Q : K;
#pragma unroll
    for (int nt = 0; nt < 4; nt++)
#pragma unroll
      for (int r = 0; r < 4; r++) {
        int m = row0 + 16 * rb + quad * 4 + r;
        int n = 64 * ch + 16 * nt + l15;
        out[(size_t)m * HS + n] = f2bf(acc[nt][r]);
      }
  } else {
#pragma unroll
    for (int nt = 0; nt < 4; nt++) {
      int n = 64 * ch + 16 * nt + l15;
      int mb = row0 + 16 * rb + quad * 4;
      us4 pk;
#pragma unroll
      for (int r = 0; r < 4; r++) pk[r] = f2bf(acc[nt][r]);
      *(us4*)(Vt + (size_t)n * T_TOK + mb) = pk;
    }
  }
}

// ---------------------------------------------------------------------------
// Split-KV flash attention. grid (64 qtiles, NCH chunks); block (qtile,ch)
// handles KV tiles [4ch, min(4ch+3, qtile)] and emits fp32 partial O + m,l.
// Dense slot index: slot(q,ch) = 64*ch - 2*ch*(ch-1) + (q - 4*ch).
// ---------------------------------------------------------------------------
__global__ __launch_bounds__(256, 2) void attn_split_kernel(
    const u16* __restrict__ Q, const u16* __restrict__ Kg,
    const u16* __restrict__ Vt, float* __restrict__ Opart,
    float* __restrict__ mstat, float* __restrict__ lstat)
{
  __shared__ __align__(16) u16 Ks[2][64 * 128];   // 2 x 16 KB
  __shared__ __align__(16) u16 Vs[2][128 * 64];   // 2 x 16 KB
  __shared__ __align__(16) u16 Ps[4 * 16 * 64];   // 8 KB (per-wave P)

  const int qtile = 63 - (int)blockIdx.x;         // heavy blocks first
  const int ch = blockIdx.y;
  if (4 * ch > qtile) return;
  const int t0 = 4 * ch;
  const int nsteps = min(CKV, qtile + 1 - t0);
  const int q0 = qtile * 64;
  const int slot = 64 * ch - 2 * ch * (ch - 1) + (qtile - 4 * ch);

  const int tid = threadIdx.x;
  const int wv = tid >> 6, lane = tid & 63, l15 = lane & 15, quad = lane >> 4;

  // Q A-frags: A[m=l15][k=quad*8+j]
  bf16x8 qf[4];
#pragma unroll
  for (int kc = 0; kc < 4; kc++)
    qf[kc] = *(const bf16x8*)(Q + (size_t)(q0 + 16 * wv + l15) * HS + kc * 32 + quad * 8);

  f32x4 o[8];
#pragma unroll
  for (int i = 0; i < 8; i++) o[i] = (f32x4)0.0f;
  float mrun[4], lrun[4];
#pragma unroll
  for (int r = 0; r < 4; r++) { mrun[r] = -1e30f; lrun[r] = 0.0f; }

  const float sc = 0.12752761571239668f; // log2(e)/sqrt(128)

  auto stage = [&](int t, int buf) {
#pragma unroll
    for (int j = 0; j < 4; j++) {
      int s = (wv * 4 + j) * 64 + lane;
      int n = s >> 4, cs = s & 15, c = cs ^ (n & 7);
      async_ld16(Kg + (size_t)(t * 64 + n) * HS + c * 8,
                 (char*)Ks[buf] + (size_t)(wv * 4 + j) * 1024);
    }
#pragma unroll
    for (int j = 0; j < 4; j++) {
      int s = (wv * 4 + j) * 64 + lane;
      int vr = s >> 3, cs = s & 7, c = cs ^ (vr & 7);
      async_ld16(Vt + (size_t)vr * T_TOK + t * 64 + c * 8,
                 (char*)Vs[buf] + (size_t)(wv * 4 + j) * 1024);
    }
  };

  stage(t0, 0);
  for (int i = 0; i < nsteps; i++) {
    const int cur = i & 1;
    const int t = t0 + i;
    __syncthreads();                           // drains loads for buf cur
    if (i + 1 < nsteps) stage(t + 1, 1 - cur); // prefetch overlaps compute

    // S = Q K^T
    f32x4 sacc[4];
#pragma unroll
    for (int nt = 0; nt < 4; nt++) sacc[nt] = (f32x4)0.0f;
#pragma unroll
    for (int kc = 0; kc < 4; kc++) {
      const int cl = kc * 4 + quad;
#pragma unroll
      for (int nt = 0; nt < 4; nt++) {
        int n = 16 * nt + l15;
        bf16x8 b = *(const bf16x8*)((const char*)Ks[cur] + (n * 16 + (cl ^ (n & 7))) * 16);
        sacc[nt] = __builtin_amdgcn_mfma_f32_16x16x32_bf16(qf[kc], b, sacc[nt], 0, 0, 0);
      }
    }

    // scale into log2 domain + causal mask (diagonal tile only)
    float s2[4][4];
    const bool diag = (t == qtile);
#pragma unroll
    for (int nt = 0; nt < 4; nt++)
#pragma unroll
      for (int r = 0; r < 4; r++) {
        float v = sacc[nt][r] * sc;
        if (diag) {
          int qr = q0 + 16 * wv + quad * 4 + r;
          int kr = t * 64 + 16 * nt + l15;
          if (kr > qr) v = -1e30f;
        }
        s2[nt][r] = v;
      }

    // online softmax; each row lives in the 16 lanes of one quad
    float mnew[4], alpha[4];
#pragma unroll
    for (int r = 0; r < 4; r++) {
      float tmax = fmaxf(fmaxf(s2[0][r], s2[1][r]), fmaxf(s2[2][r], s2[3][r]));
#pragma unroll
      for (int off = 1; off < 16; off <<= 1) tmax = fmaxf(tmax, __shfl_xor(tmax, off));
      mnew[r] = fmaxf(mrun[r], tmax);
      alpha[r] = exp2f(mrun[r] - mnew[r]);
      mrun[r] = mnew[r];
    }
    float p[4][4];
#pragma unroll
    for (int r = 0; r < 4; r++) {
      float s = 0.0f;
#pragma unroll
      for (int nt = 0; nt < 4; nt++) { p[nt][r] = exp2f(s2[nt][r] - mnew[r]); s += p[nt][r]; }
#pragma unroll
      for (int off = 1; off < 16; off <<= 1) s += __shfl_xor(s, off);
      lrun[r] = lrun[r] * alpha[r] + s;
    }
#pragma unroll
    for (int c = 0; c < 8; c++)
#pragma unroll
      for (int r = 0; r < 4; r++) o[c][r] *= alpha[r];

    // P: C-layout -> per-wave LDS (no barrier: DS in-order, Ps wave-private)
    u16* Pw = Ps + wv * 1024;
#pragma unroll
    for (int nt = 0; nt < 4; nt++)
#pragma unroll
      for (int r = 0; r < 4; r++) {
        int row = quad * 4 + r;
        int col = nt * 16 + l15;
        int cc = col >> 3, wi = col & 7;
        Pw[(row * 8 + (cc ^ (row & 7))) * 8 + wi] = f2bf(p[nt][r]);
      }

    // O += P V
#pragma unroll
    for (int kc = 0; kc < 2; kc++) {
      const int cl = kc * 4 + quad;
      bf16x8 a = *(const bf16x8*)((const char*)Pw + (l15 * 8 + (cl ^ (l15 & 7))) * 16);
#pragma unroll
      for (int c = 0; c < 8; c++) {
        int vr = 16 * c + l15;
        bf16x8 b = *(const bf16x8*)((const char*)Vs[cur] + (vr * 8 + (cl ^ (vr & 7))) * 16);
        o[c] = __builtin_amdgcn_mfma_f32_16x16x32_bf16(a, b, o[c], 0, 0, 0);
      }
    }
  }

  // store fp32 partial O + stats
  float* po = Opart + (size_t)slot * 64 * 128;
#pragma unroll
  for (int c = 0; c < 8; c++)
#pragma unroll
    for (int r = 0; r < 4; r++) {
      int ml = 16 * wv + quad * 4 + r;
      po[ml * 128 + 16 * c + l15] = o[c][r];
    }
  if (l15 == 0) {
#pragma unroll
    for (int r = 0; r < 4; r++) {
      int ml = 16 * wv + quad * 4 + r;
      mstat[slot * 64 + ml] = mrun[r];
      lstat[slot * 64 + ml] = lrun[r];
    }
  }
}

// ---------------------------------------------------------------------------
// Combine partials. grid (64 qtiles, 4 col-blocks), 256 threads.
// Thread handles one row x 8 cols. Output dtype per detected flag.
// ---------------------------------------------------------------------------
__global__ __launch_bounds__(256) void combine_kernel(
    const float* __restrict__ Opart, const float* __restrict__ mstat,
    const float* __restrict__ lstat, void* __restrict__ out_v,
    const int* __restrict__ dflag)
{
  const int q = blockIdx.x;
  const int cb = blockIdx.y;
  const int tid = threadIdx.x;
  const int row = tid >> 2;
  const int col = cb * 32 + (tid & 3) * 8;
  const int nch = (q + 4) / 4;   // ceil((q+1)/4)
  const bool of32 = (*dflag != 0);

  float M = -1e30f;
  {
    int base = 0;
    for (int c = 0; c < nch; c++) {
      int s = base + q - 4 * c;
      M = fmaxf(M, mstat[s * 64 + row]);
      base += 64 - 4 * c;
    }
  }
  float l = 0.0f;
  float acc[8];
#pragma unroll
  for (int j = 0; j < 8; j++) acc[j] = 0.0f;
  {
    int base = 0;
    for (int c = 0; c < nch; c++) {
      int s = base + q - 4 * c;
      float w = exp2f(mstat[s * 64 + row] - M);
      l += w * lstat[s * 64 + row];
      const float* op = Opart + ((size_t)s * 64 + row) * 128 + col;
      f32x4 a = *(const f32x4*)op;
      f32x4 b = *(const f32x4*)(op + 4);
#pragma unroll
      for (int j = 0; j < 4; j++) { acc[j] += w * a[j]; acc[4 + j] += w * b[j]; }
      base += 64 - 4 * c;
    }
  }
  const float inv = 1.0f / l;
  const size_t goff = (size_t)(q * 64 + row) * HS + col;
  if (of32) {
    float* out = (float*)out_v + goff;
    f32x4 r0, r1;
#pragma unroll
    for (int j = 0; j < 4; j++) { r0[j] = acc[j] * inv; r1[j] = acc[4 + j] * inv; }
    *(f32x4*)out = r0;
    *(f32x4*)(out + 4) = r1;
  } else {
    u16* out = (u16*)out_v + goff;
    us4 r0, r1;
#pragma unroll
    for (int j = 0; j < 4; j++) { r0[j] = f2bf(acc[j] * inv); r1[j] = f2bf(acc[4 + j] * inv); }
    *(us4*)out = r0;
    *(us4*)(out + 4) = r1;
  }
}

extern "C" void kernel_launch(void* const* d_in, const int* in_sizes, int n_in,
                              void* d_out, int out_size, void* d_ws, size_t ws_size,
                              hipStream_t stream) {
  const u16* x  = (const u16*)d_in[0];
  const u16* Wq = (const u16*)d_in[1];
  const u16* Wk = (const u16*)d_in[2];
  const u16* Wv = (const u16*)d_in[3];

  // ws layout (u16 units). The first region (partials) is written only by
  // attn_split, after qkv is done; Wb/Q/K/Vt live beyond it.
  float* Opart = (float*)d_ws;                   // 544 * 64*128 fp32 (17.8 MB)
  float* mstat = Opart + (size_t)544 * 64 * 128;
  float* lstat = mstat + (size_t)544 * 64;

  u16* Wqb = (u16*)(lstat + (size_t)544 * 64);   // 3 x 128*2048 bf16
  u16* Wkb = Wqb + (size_t)HS * D_IN;
  u16* Wvb = Wkb + (size_t)HS * D_IN;
  u16* Q   = Wvb + (size_t)HS * D_IN;            // 4096*128 bf16 each
  u16* K   = Q   + (size_t)T_TOK * HS;
  u16* Vt  = K   + (size_t)T_TOK * HS;
  int* flag = (int*)(Vt + (size_t)T_TOK * HS);

  conv3_kernel<<<384, 256, 0, stream>>>(Wq, Wk, Wv, Wqb, Wkb, Wvb, flag);
  qkv_kernel<<<dim3(128, 3), 256, 0, stream>>>(x, Wqb, Wkb, Wvb, Q, K, Vt);
  attn_split_kernel<<<dim3(64, NCH), 256, 0, stream>>>(Q, K, Vt, Opart, mstat, lstat);
  combine_kernel<<<dim3(64, 4), 256, 0, stream>>>(Opart, mstat, lstat, d_out, flag);
}

// Round 13
// 157.068 us; speedup vs baseline: 1.2526x; 1.2526x over previous
//
#include <hip/hip_runtime.h>
#include <hip/hip_bf16.h>

#define T_TOK 4096
#define D_IN  2048
#define HS    128
#define CKV   4      // KV tiles per attention chunk
#define NCH   16     // ceil(64 / CKV)

typedef unsigned short u16;
typedef __attribute__((ext_vector_type(8))) __bf16 bf16x8;
typedef __attribute__((ext_vector_type(4))) float f32x4;
typedef __attribute__((ext_vector_type(4))) unsigned short us4;
typedef __attribute__((ext_vector_type(8))) unsigned short us8;

#define GLOBAL_AS __attribute__((address_space(1)))
#define LDS_AS    __attribute__((address_space(3)))

__device__ __forceinline__ void async_ld16(const void* g, void* l) {
  __builtin_amdgcn_global_load_lds((GLOBAL_AS void*)(void*)g, (LDS_AS void*)l, 16, 0, 0);
}

__device__ __forceinline__ u16 f2bf(float v) {
  return __builtin_bit_cast(u16, __float2bfloat16(v));
}

// ---------------------------------------------------------------------------
// fp32-vs-bf16 autodetect on a buffer head: even u16s of fp32 data are raw
// low-mantissa bits -> ~25% have "exponent" field >= 0xBF; genuine bf16
// N(0,s) has none. Returns wave-uniform flag via LDS broadcast.
// ---------------------------------------------------------------------------
__device__ __forceinline__ bool detect_f32(const u16* in, int tid, int* sflag) {
  if (tid < 64) {
    int cnt = 0;
#pragma unroll
    for (int j = 0; j < 8; j++) {
      u16 v = in[(tid * 8 + j) * 2];
      cnt += (((v >> 7) & 0xFF) >= 0xBF) ? 1 : 0;
    }
#pragma unroll
    for (int off = 1; off < 64; off <<= 1) cnt += __shfl_xor(cnt, off);
    if (tid == 0) *sflag = (cnt > 8) ? 1 : 0;
  }
  __syncthreads();
  return (*sflag != 0);
}

// ---------------------------------------------------------------------------
// Weight normalizer: all three matrices, 128 blocks each; converts fp32->bf16
// (or copies bf16). mat0/blk0 publishes the dtype flag for the epilogue.
// ---------------------------------------------------------------------------
__global__ __launch_bounds__(256) void conv3_kernel(
    const u16* __restrict__ w0, const u16* __restrict__ w1,
    const u16* __restrict__ w2, u16* __restrict__ o0,
    u16* __restrict__ o1, u16* __restrict__ o2, int* __restrict__ flag) {
  __shared__ int sflag;
  const int mat = blockIdx.x >> 7;
  const int blk = blockIdx.x & 127;
  const u16* in = (mat == 0) ? w0 : ((mat == 1) ? w1 : w2);
  u16* out = (mat == 0) ? o0 : ((mat == 1) ? o1 : o2);
  const int tid = threadIdx.x;
  const bool isf32 = detect_f32(in, tid, &sflag);
  if (tid == 0 && mat == 0 && blk == 0) *flag = isf32 ? 1 : 0;
  const size_t base = ((size_t)blk * 256 + tid) * 8;
  if (isf32) {
    const float* f = (const float*)in;
    us4 a, b;
#pragma unroll
    for (int j = 0; j < 4; j++) a[j] = f2bf(f[base + j]);
#pragma unroll
    for (int j = 0; j < 4; j++) b[j] = f2bf(f[base + 4 + j]);
    *(us4*)(out + base) = a;
    *(us4*)(out + base + 4) = b;
  } else {
    *(us8*)(out + base) = *(const us8*)(in + base);
  }
}

// ---------------------------------------------------------------------------
// QKV projection v6: BM=32, BK=128 — cut serial K-slots 32 -> 16.
// Slot model (rounds 7-10): wall = slots x ~3450cyc, slots = iters/block /
// blocks-per-CU; every earlier config landed at 32 slots. v6: 16 iters,
// LDS 80 KB (A 2x8 + B 2x32) -> 2 blocks/CU, grid 384 <= 512 -> all
// resident, one batch -> 16 slots. Proven v3 staged structure otherwise.
// 4 waves: rband=wv&1 (16 rows), chalf=wv>>1 (64 cols).
// Swizzled 16B chunks (16/row): chunk (row r, c) at slot r*16 + (c ^ (r&7)).
// fp32 x path: reg-prefetch float4 + cvt + ds_write (2 chunks/thread);
// bf16 x path: 2 asyncs/thread. Weights: 8 asyncs/thread.
// ---------------------------------------------------------------------------
__global__ __launch_bounds__(256, 2) void qkv_kernel(
    const u16* __restrict__ x, const u16* __restrict__ Wq,
    const u16* __restrict__ Wk, const u16* __restrict__ Wv,
    u16* __restrict__ Q, u16* __restrict__ K, u16* __restrict__ Vt)
{
  __shared__ __align__(16) u16 As[2][32 * 128];    // 2 x 8 KB
  __shared__ __align__(16) u16 Bs[2][128 * 128];   // 2 x 32 KB
  __shared__ int sflag;

  const int mat = blockIdx.y;
  const u16* W = (mat == 0) ? Wq : ((mat == 1) ? Wk : Wv);
  const int mtile = blockIdx.x;
  const int tid = threadIdx.x;
  const int wv = tid >> 6, lane = tid & 63, l15 = lane & 15, quad = lane >> 4;
  const int rband = wv & 1, chalf = wv >> 1;
  const int row0 = mtile * 32;

  const bool isf32 = detect_f32(x, tid, &sflag);

  f32x4 acc[4];
#pragma unroll
  for (int i = 0; i < 4; i++) acc[i] = (f32x4)0.0f;

  // A: 32x128 bf16 = 512 chunks of 16B, 16/row; thread owns slots 2t, 2t+1
  const int ar  = tid >> 3;                       // row 0..31
  const int ac0 = ((2 * tid) & 15) ^ (ar & 7);    // global chunk for slot 2t
  const int ac1 = ((2 * tid + 1) & 15) ^ (ar & 7);

  f32x4 pa[4];                             // prefetched fp32 A data (2 chunks)
  auto loadA_f32 = [&](int k0) {
    const float* xf = (const float*)x + (size_t)(row0 + ar) * D_IN + k0;
    pa[0] = *(const f32x4*)(xf + ac0 * 8);
    pa[1] = *(const f32x4*)(xf + ac0 * 8 + 4);
    pa[2] = *(const f32x4*)(xf + ac1 * 8);
    pa[3] = *(const f32x4*)(xf + ac1 * 8 + 4);
  };
  auto writeA_f32 = [&](int buf) {
    us8 c0, c1;
#pragma unroll
    for (int j = 0; j < 4; j++) {
      c0[j] = f2bf(pa[0][j]); c0[4 + j] = f2bf(pa[1][j]);
      c1[j] = f2bf(pa[2][j]); c1[4 + j] = f2bf(pa[3][j]);
    }
    *(us8*)((char*)As[buf] + (size_t)(2 * tid) * 16) = c0;
    *(us8*)((char*)As[buf] + (size_t)(2 * tid + 1) * 16) = c1;
  };
  auto stageA_bf16 = [&](int k0, int buf) {
#pragma unroll
    for (int j = 0; j < 2; j++) {
      int s = (wv * 2 + j) * 64 + lane;
      int r = s >> 4, cs = s & 15, c = cs ^ (r & 7);
      async_ld16(x + (size_t)(row0 + r) * D_IN + k0 + c * 8,
                 (char*)As[buf] + (size_t)(wv * 2 + j) * 1024);
    }
  };
  auto stageB = [&](int k0, int buf) {
#pragma unroll
    for (int j = 0; j < 8; j++) {
      int s = (wv * 8 + j) * 64 + lane;
      int n = s >> 4, cs = s & 15, c = cs ^ (n & 7);
      async_ld16(W + (size_t)n * D_IN + k0 + c * 8,
                 (char*)Bs[buf] + (size_t)(wv * 8 + j) * 1024);
    }
  };

  stageB(0, 0);
  if (isf32) loadA_f32(0); else stageA_bf16(0, 0);

  for (int kt = 0; kt < 16; kt++) {
    const int cur = kt & 1;
    if (isf32) writeA_f32(cur);          // A(kt) regs -> LDS cur
    __syncthreads();                     // drains A writes + asyncs for cur
    if (kt < 15) {                       // prefetch overlaps compute
      stageB((kt + 1) * 128, 1 - cur);
      if (isf32) loadA_f32((kt + 1) * 128); else stageA_bf16((kt + 1) * 128, 1 - cur);
    }
#pragma unroll
    for (int kc = 0; kc < 4; kc++) {
      const int rA = 16 * rband + l15;
      const int cl = kc * 4 + quad;
      bf16x8 a = *(const bf16x8*)((const char*)As[cur] + (rA * 16 + (cl ^ (rA & 7))) * 16);
#pragma unroll
      for (int nt = 0; nt < 4; nt++) {
        int n = chalf * 64 + 16 * nt + l15;
        bf16x8 b = *(const bf16x8*)((const char*)Bs[cur] + (n * 16 + (cl ^ (n & 7))) * 16);
        acc[nt] = __builtin_amdgcn_mfma_f32_16x16x32_bf16(a, b, acc[nt], 0, 0, 0);
      }
    }
  }

  // epilogue. D-frag: row = quad*4 + r, col = 16*nt + l15 (within wave tile)
  if (mat < 2) {
    u16* out = (mat == 0) ? Q : K;
#pragma unroll
    for (int nt = 0; nt < 4; nt++)
#pragma unroll
      for (int r = 0; r < 4; r++) {
        int m = row0 + 16 * rband + quad * 4 + r;
        int n = chalf * 64 + 16 * nt + l15;
        out[(size_t)m * HS + n] = f2bf(acc[nt][r]);
      }
  } else {
#pragma unroll
    for (int nt = 0; nt < 4; nt++) {
      int n = chalf * 64 + 16 * nt + l15;
      int mb = row0 + 16 * rband + quad * 4;
      us4 pk;
#pragma unroll
      for (int r = 0; r < 4; r++) pk[r] = f2bf(acc[nt][r]);
      *(us4*)(Vt + (size_t)n * T_TOK + mb) = pk;
    }
  }
}

// ---------------------------------------------------------------------------
// Split-KV flash attention. grid (64 qtiles, NCH chunks); block (qtile,ch)
// handles KV tiles [4ch, min(4ch+3, qtile)] and emits fp32 partial O + m,l.
// Dense slot index: slot(q,ch) = 64*ch - 2*ch*(ch-1) + (q - 4*ch).
// ---------------------------------------------------------------------------
__global__ __launch_bounds__(256, 2) void attn_split_kernel(
    const u16* __restrict__ Q, const u16* __restrict__ Kg,
    const u16* __restrict__ Vt, float* __restrict__ Opart,
    float* __restrict__ mstat, float* __restrict__ lstat)
{
  __shared__ __align__(16) u16 Ks[2][64 * 128];   // 2 x 16 KB
  __shared__ __align__(16) u16 Vs[2][128 * 64];   // 2 x 16 KB
  __shared__ __align__(16) u16 Ps[4 * 16 * 64];   // 8 KB (per-wave P)

  const int qtile = 63 - (int)blockIdx.x;         // heavy blocks first
  const int ch = blockIdx.y;
  if (4 * ch > qtile) return;
  const int t0 = 4 * ch;
  const int nsteps = min(CKV, qtile + 1 - t0);
  const int q0 = qtile * 64;
  const int slot = 64 * ch - 2 * ch * (ch - 1) + (qtile - 4 * ch);

  const int tid = threadIdx.x;
  const int wv = tid >> 6, lane = tid & 63, l15 = lane & 15, quad = lane >> 4;

  // Q A-frags: A[m=l15][k=quad*8+j]
  bf16x8 qf[4];
#pragma unroll
  for (int kc = 0; kc < 4; kc++)
    qf[kc] = *(const bf16x8*)(Q + (size_t)(q0 + 16 * wv + l15) * HS + kc * 32 + quad * 8);

  f32x4 o[8];
#pragma unroll
  for (int i = 0; i < 8; i++) o[i] = (f32x4)0.0f;
  float mrun[4], lrun[4];
#pragma unroll
  for (int r = 0; r < 4; r++) { mrun[r] = -1e30f; lrun[r] = 0.0f; }

  const float sc = 0.12752761571239668f; // log2(e)/sqrt(128)

  auto stage = [&](int t, int buf) {
#pragma unroll
    for (int j = 0; j < 4; j++) {
      int s = (wv * 4 + j) * 64 + lane;
      int n = s >> 4, cs = s & 15, c = cs ^ (n & 7);
      async_ld16(Kg + (size_t)(t * 64 + n) * HS + c * 8,
                 (char*)Ks[buf] + (size_t)(wv * 4 + j) * 1024);
    }
#pragma unroll
    for (int j = 0; j < 4; j++) {
      int s = (wv * 4 + j) * 64 + lane;
      int vr = s >> 3, cs = s & 7, c = cs ^ (vr & 7);
      async_ld16(Vt + (size_t)vr * T_TOK + t * 64 + c * 8,
                 (char*)Vs[buf] + (size_t)(wv * 4 + j) * 1024);
    }
  };

  stage(t0, 0);
  for (int i = 0; i < nsteps; i++) {
    const int cur = i & 1;
    const int t = t0 + i;
    __syncthreads();                           // drains loads for buf cur
    if (i + 1 < nsteps) stage(t + 1, 1 - cur); // prefetch overlaps compute

    // S = Q K^T
    f32x4 sacc[4];
#pragma unroll
    for (int nt = 0; nt < 4; nt++) sacc[nt] = (f32x4)0.0f;
#pragma unroll
    for (int kc = 0; kc < 4; kc++) {
      const int cl = kc * 4 + quad;
#pragma unroll
      for (int nt = 0; nt < 4; nt++) {
        int n = 16 * nt + l15;
        bf16x8 b = *(const bf16x8*)((const char*)Ks[cur] + (n * 16 + (cl ^ (n & 7))) * 16);
        sacc[nt] = __builtin_amdgcn_mfma_f32_16x16x32_bf16(qf[kc], b, sacc[nt], 0, 0, 0);
      }
    }

    // scale into log2 domain + causal mask (diagonal tile only)
    float s2[4][4];
    const bool diag = (t == qtile);
#pragma unroll
    for (int nt = 0; nt < 4; nt++)
#pragma unroll
      for (int r = 0; r < 4; r++) {
        float v = sacc[nt][r] * sc;
        if (diag) {
          int qr = q0 + 16 * wv + quad * 4 + r;
          int kr = t * 64 + 16 * nt + l15;
          if (kr > qr) v = -1e30f;
        }
        s2[nt][r] = v;
      }

    // online softmax; each row lives in the 16 lanes of one quad
    float mnew[4], alpha[4];
#pragma unroll
    for (int r = 0; r < 4; r++) {
      float tmax = fmaxf(fmaxf(s2[0][r], s2[1][r]), fmaxf(s2[2][r], s2[3][r]));
#pragma unroll
      for (int off = 1; off < 16; off <<= 1) tmax = fmaxf(tmax, __shfl_xor(tmax, off));
      mnew[r] = fmaxf(mrun[r], tmax);
      alpha[r] = exp2f(mrun[r] - mnew[r]);
      mrun[r] = mnew[r];
    }
    float p[4][4];
#pragma unroll
    for (int r = 0; r < 4; r++) {
      float s = 0.0f;
#pragma unroll
      for (int nt = 0; nt < 4; nt++) { p[nt][r] = exp2f(s2[nt][r] - mnew[r]); s += p[nt][r]; }
#pragma unroll
      for (int off = 1; off < 16; off <<= 1) s += __shfl_xor(s, off);
      lrun[r] = lrun[r] * alpha[r] + s;
    }
#pragma unroll
    for (int c = 0; c < 8; c++)
#pragma unroll
      for (int r = 0; r < 4; r++) o[c][r] *= alpha[r];

    // P: C-layout -> per-wave LDS (no barrier: DS in-order, Ps wave-private)
    u16* Pw = Ps + wv * 1024;
#pragma unroll
    for (int nt = 0; nt < 4; nt++)
#pragma unroll
      for (int r = 0; r < 4; r++) {
        int row = quad * 4 + r;
        int col = nt * 16 + l15;
        int cc = col >> 3, wi = col & 7;
        Pw[(row * 8 + (cc ^ (row & 7))) * 8 + wi] = f2bf(p[nt][r]);
      }

    // O += P V
#pragma unroll
    for (int kc = 0; kc < 2; kc++) {
      const int cl = kc * 4 + quad;
      bf16x8 a = *(const bf16x8*)((const char*)Pw + (l15 * 8 + (cl ^ (l15 & 7))) * 16);
#pragma unroll
      for (int c = 0; c < 8; c++) {
        int vr = 16 * c + l15;
        bf16x8 b = *(const bf16x8*)((const char*)Vs[cur] + (vr * 8 + (cl ^ (vr & 7))) * 16);
        o[c] = __builtin_amdgcn_mfma_f32_16x16x32_bf16(a, b, o[c], 0, 0, 0);
      }
    }
  }

  // store fp32 partial O + stats
  float* po = Opart + (size_t)slot * 64 * 128;
#pragma unroll
  for (int c = 0; c < 8; c++)
#pragma unroll
    for (int r = 0; r < 4; r++) {
      int ml = 16 * wv + quad * 4 + r;
      po[ml * 128 + 16 * c + l15] = o[c][r];
    }
  if (l15 == 0) {
#pragma unroll
    for (int r = 0; r < 4; r++) {
      int ml = 16 * wv + quad * 4 + r;
      mstat[slot * 64 + ml] = mrun[r];
      lstat[slot * 64 + ml] = lrun[r];
    }
  }
}

// ---------------------------------------------------------------------------
// Combine partials. grid (64 qtiles, 4 col-blocks), 256 threads.
// Thread handles one row x 8 cols. Output dtype per detected flag.
// ---------------------------------------------------------------------------
__global__ __launch_bounds__(256) void combine_kernel(
    const float* __restrict__ Opart, const float* __restrict__ mstat,
    const float* __restrict__ lstat, void* __restrict__ out_v,
    const int* __restrict__ dflag)
{
  const int q = blockIdx.x;
  const int cb = blockIdx.y;
  const int tid = threadIdx.x;
  const int row = tid >> 2;
  const int col = cb * 32 + (tid & 3) * 8;
  const int nch = (q + 4) / 4;   // ceil((q+1)/4)
  const bool of32 = (*dflag != 0);

  float M = -1e30f;
  {
    int base = 0;
    for (int c = 0; c < nch; c++) {
      int s = base + q - 4 * c;
      M = fmaxf(M, mstat[s * 64 + row]);
      base += 64 - 4 * c;
    }
  }
  float l = 0.0f;
  float acc[8];
#pragma unroll
  for (int j = 0; j < 8; j++) acc[j] = 0.0f;
  {
    int base = 0;
    for (int c = 0; c < nch; c++) {
      int s = base + q - 4 * c;
      float w = exp2f(mstat[s * 64 + row] - M);
      l += w * lstat[s * 64 + row];
      const float* op = Opart + ((size_t)s * 64 + row) * 128 + col;
      f32x4 a = *(const f32x4*)op;
      f32x4 b = *(const f32x4*)(op + 4);
#pragma unroll
      for (int j = 0; j < 4; j++) { acc[j] += w * a[j]; acc[4 + j] += w * b[j]; }
      base += 64 - 4 * c;
    }
  }
  const float inv = 1.0f / l;
  const size_t goff = (size_t)(q * 64 + row) * HS + col;
  if (of32) {
    float* out = (float*)out_v + goff;
    f32x4 r0, r1;
#pragma unroll
    for (int j = 0; j < 4; j++) { r0[j] = acc[j] * inv; r1[j] = acc[4 + j] * inv; }
    *(f32x4*)out = r0;
    *(f32x4*)(out + 4) = r1;
  } else {
    u16* out = (u16*)out_v + goff;
    us4 r0, r1;
#pragma unroll
    for (int j = 0; j < 4; j++) { r0[j] = f2bf(acc[j] * inv); r1[j] = f2bf(acc[4 + j] * inv); }
    *(us4*)out = r0;
    *(us4*)(out + 4) = r1;
  }
}

extern "C" void kernel_launch(void* const* d_in, const int* in_sizes, int n_in,
                              void* d_out, int out_size, void* d_ws, size_t ws_size,
                              hipStream_t stream) {
  const u16* x  = (const u16*)d_in[0];
  const u16* Wq = (const u16*)d_in[1];
  const u16* Wk = (const u16*)d_in[2];
  const u16* Wv = (const u16*)d_in[3];

  // ws layout (u16 units). The first region (partials) is written only by
  // attn_split, after qkv is done; Wb/Q/K/Vt live beyond it.
  float* Opart = (float*)d_ws;                   // 544 * 64*128 fp32 (17.8 MB)
  float* mstat = Opart + (size_t)544 * 64 * 128;
  float* lstat = mstat + (size_t)544 * 64;

  u16* Wqb = (u16*)(lstat + (size_t)544 * 64);   // 3 x 128*2048 bf16
  u16* Wkb = Wqb + (size_t)HS * D_IN;
  u16* Wvb = Wkb + (size_t)HS * D_IN;
  u16* Q   = Wvb + (size_t)HS * D_IN;            // 4096*128 bf16 each
  u16* K   = Q   + (size_t)T_TOK * HS;
  u16* Vt  = K   + (size_t)T_TOK * HS;
  int* flag = (int*)(Vt + (size_t)T_TOK * HS);

  conv3_kernel<<<384, 256, 0, stream>>>(Wq, Wk, Wv, Wqb, Wkb, Wvb, flag);
  qkv_kernel<<<dim3(128, 3), 256, 0, stream>>>(x, Wqb, Wkb, Wvb, Q, K, Vt);
  attn_split_kernel<<<dim3(64, NCH), 256, 0, stream>>>(Q, K, Vt, Opart, mstat, lstat);
  combine_kernel<<<dim3(64, 4), 256, 0, stream>>>(Opart, mstat, lstat, d_out, flag);
}

// Round 14
// 142.674 us; speedup vs baseline: 1.3790x; 1.1009x over previous
//
#include <hip/hip_runtime.h>
#include <hip/hip_bf16.h>

#define T_TOK 4096
#define D_IN  2048
#define HS    128
#define CKV   4      // KV tiles per attention chunk
#define NCH   16     // ceil(64 / CKV)

typedef unsigned short u16;
typedef __attribute__((ext_vector_type(8))) __bf16 bf16x8;
typedef __attribute__((ext_vector_type(4))) float f32x4;
typedef __attribute__((ext_vector_type(4))) unsigned short us4;
typedef __attribute__((ext_vector_type(8))) unsigned short us8;

#define GLOBAL_AS __attribute__((address_space(1)))
#define LDS_AS    __attribute__((address_space(3)))

__device__ __forceinline__ void async_ld16(const void* g, void* l) {
  __builtin_amdgcn_global_load_lds((GLOBAL_AS void*)(void*)g, (LDS_AS void*)l, 16, 0, 0);
}

__device__ __forceinline__ u16 f2bf(float v) {
  return __builtin_bit_cast(u16, __float2bfloat16(v));
}

// ---------------------------------------------------------------------------
// fp32-vs-bf16 autodetect on a buffer head (see earlier rounds).
// ---------------------------------------------------------------------------
__device__ __forceinline__ bool detect_f32(const u16* in, int tid, int* sflag) {
  if (tid < 64) {
    int cnt = 0;
#pragma unroll
    for (int j = 0; j < 8; j++) {
      u16 v = in[(tid * 8 + j) * 2];
      cnt += (((v >> 7) & 0xFF) >= 0xBF) ? 1 : 0;
    }
#pragma unroll
    for (int off = 1; off < 64; off <<= 1) cnt += __shfl_xor(cnt, off);
    if (tid == 0) *sflag = (cnt > 8) ? 1 : 0;
  }
  __syncthreads();
  return (*sflag != 0);
}

// ---------------------------------------------------------------------------
// Weight normalizer: 3 matrices, 128 blocks each; fp32->bf16 (or copy).
// ---------------------------------------------------------------------------
__global__ __launch_bounds__(256) void conv3_kernel(
    const u16* __restrict__ w0, const u16* __restrict__ w1,
    const u16* __restrict__ w2, u16* __restrict__ o0,
    u16* __restrict__ o1, u16* __restrict__ o2, int* __restrict__ flag) {
  __shared__ int sflag;
  const int mat = blockIdx.x >> 7;
  const int blk = blockIdx.x & 127;
  const u16* in = (mat == 0) ? w0 : ((mat == 1) ? w1 : w2);
  u16* out = (mat == 0) ? o0 : ((mat == 1) ? o1 : o2);
  const int tid = threadIdx.x;
  const bool isf32 = detect_f32(in, tid, &sflag);
  if (tid == 0 && mat == 0 && blk == 0) *flag = isf32 ? 1 : 0;
  const size_t base = ((size_t)blk * 256 + tid) * 8;
  if (isf32) {
    const float* f = (const float*)in;
    us4 a, b;
#pragma unroll
    for (int j = 0; j < 4; j++) a[j] = f2bf(f[base + j]);
#pragma unroll
    for (int j = 0; j < 4; j++) b[j] = f2bf(f[base + 4 + j]);
    *(us4*)(out + base) = a;
    *(us4*)(out + base + 4) = b;
  } else {
    *(us8*)(out + base) = *(const us8*)(in + base);
  }
}

// ---------------------------------------------------------------------------
// QKV projection v7: K-split. grid (64 mtiles, 3 mats, 4 kslices) = 768
// blocks (3/CU). Each block: BM=64, K-range 512 = 8 iters of BK=64 (the
// R7-verified staged structure), writes fp32 partials.
// Rationale (R7/R10/R13 post-mortems): wall = staged bytes/CU at ~22 B/cyc;
// R10's 492 MB was 78% redundant W re-staging (BM=16 -> W staged 256x).
// K-split at BM=64 stages W once per (mtile,kslice): 192 MB total.
// Partial layout: mat<2 -> [m][n] (64x128); mat2 -> [n][m] (128x64, i.e.
// pre-transposed for Vt) so the reduce pass is fully coalesced both ways.
// ---------------------------------------------------------------------------
__global__ __launch_bounds__(256, 2) void qkv_kernel(
    const u16* __restrict__ x, const u16* __restrict__ Wq,
    const u16* __restrict__ Wk, const u16* __restrict__ Wv,
    float* __restrict__ Ppart)
{
  __shared__ __align__(16) u16 As[2][64 * 64];    // 2 x 8 KB
  __shared__ __align__(16) u16 Bs[2][128 * 64];   // 2 x 16 KB
  __shared__ int sflag;

  const int mat = blockIdx.y;
  const u16* W = (mat == 0) ? Wq : ((mat == 1) ? Wk : Wv);
  const int mtile = blockIdx.x;
  const int ks = blockIdx.z;
  const int kbase = ks * 512;
  const int tid = threadIdx.x;
  const int wv = tid >> 6, lane = tid & 63, l15 = lane & 15, quad = lane >> 4;
  const int row0 = mtile * 64;

  const bool isf32 = detect_f32(x, tid, &sflag);

  f32x4 acc[8];
#pragma unroll
  for (int i = 0; i < 8; i++) acc[i] = (f32x4)0.0f;

  // A: 64x64 bf16 = 512 chunks of 16B, 8/row; thread owns slots 2t, 2t+1
  const int s0 = tid * 2;
  const int ar = s0 >> 3;                  // row 0..63
  const int ac0 = (s0 & 7) ^ (ar & 7);
  const int ac1 = ((s0 + 1) & 7) ^ (ar & 7);

  f32x4 pa[4];                             // prefetched fp32 A data
  auto loadA_f32 = [&](int k0) {
    const float* xf = (const float*)x + (size_t)(row0 + ar) * D_IN + k0;
    pa[0] = *(const f32x4*)(xf + ac0 * 8);
    pa[1] = *(const f32x4*)(xf + ac0 * 8 + 4);
    pa[2] = *(const f32x4*)(xf + ac1 * 8);
    pa[3] = *(const f32x4*)(xf + ac1 * 8 + 4);
  };
  auto writeA_f32 = [&](int buf) {
    us8 c0, c1;
#pragma unroll
    for (int j = 0; j < 4; j++) {
      c0[j] = f2bf(pa[0][j]); c0[4 + j] = f2bf(pa[1][j]);
      c1[j] = f2bf(pa[2][j]); c1[4 + j] = f2bf(pa[3][j]);
    }
    *(us8*)((char*)As[buf] + (size_t)s0 * 16) = c0;
    *(us8*)((char*)As[buf] + (size_t)(s0 + 1) * 16) = c1;
  };
  auto stageA_bf16 = [&](int k0, int buf) {
#pragma unroll
    for (int j = 0; j < 2; j++) {
      int s = (wv * 2 + j) * 64 + lane;
      int r = s >> 3, cs = s & 7, c = cs ^ (r & 7);
      async_ld16(x + (size_t)(row0 + r) * D_IN + k0 + c * 8,
                 (char*)As[buf] + (size_t)(wv * 2 + j) * 1024);
    }
  };
  auto stageB = [&](int k0, int buf) {
#pragma unroll
    for (int j = 0; j < 4; j++) {
      int s = (wv * 4 + j) * 64 + lane;
      int n = s >> 3, cs = s & 7, c = cs ^ (n & 7);
      async_ld16(W + (size_t)n * D_IN + k0 + c * 8,
                 (char*)Bs[buf] + (size_t)(wv * 4 + j) * 1024);
    }
  };

  stageB(kbase, 0);
  if (isf32) loadA_f32(kbase); else stageA_bf16(kbase, 0);

  for (int kt = 0; kt < 8; kt++) {
    const int cur = kt & 1;
    if (isf32) writeA_f32(cur);
    __syncthreads();                     // drains A writes + asyncs for cur
    if (kt < 7) {
      stageB(kbase + (kt + 1) * 64, 1 - cur);
      if (isf32) loadA_f32(kbase + (kt + 1) * 64);
      else stageA_bf16(kbase + (kt + 1) * 64, 1 - cur);
    }
#pragma unroll
    for (int kc = 0; kc < 2; kc++) {
      const int rA = 16 * wv + l15;
      const int cl = kc * 4 + quad;
      bf16x8 a = *(const bf16x8*)((const char*)As[cur] + (rA * 8 + (cl ^ (rA & 7))) * 16);
#pragma unroll
      for (int nt = 0; nt < 8; nt++) {
        int n = 16 * nt + l15;
        bf16x8 b = *(const bf16x8*)((const char*)Bs[cur] + (n * 8 + (cl ^ (n & 7))) * 16);
        acc[nt] = __builtin_amdgcn_mfma_f32_16x16x32_bf16(a, b, acc[nt], 0, 0, 0);
      }
    }
  }

  // partial write. slice base: P[((ks*3 + mat)*64 + mtile) * 8192]
  float* po = Ppart + (((size_t)ks * 3 + mat) * 64 + mtile) * 8192;
  if (mat < 2) {
    // layout [m][n]
#pragma unroll
    for (int nt = 0; nt < 8; nt++)
#pragma unroll
      for (int r = 0; r < 4; r++) {
        int m = 16 * wv + quad * 4 + r;
        int n = 16 * nt + l15;
        po[m * 128 + n] = acc[nt][r];
      }
  } else {
    // layout [n][m] (pre-transposed for Vt); 4 consecutive m -> f32x4 store
#pragma unroll
    for (int nt = 0; nt < 8; nt++) {
      int n = 16 * nt + l15;
      int mb = 16 * wv + quad * 4;
      f32x4 pk;
#pragma unroll
      for (int r = 0; r < 4; r++) pk[r] = acc[nt][r];
      *(f32x4*)(po + (size_t)n * 64 + mb) = pk;
    }
  }
}

// ---------------------------------------------------------------------------
// Reduce the 4 K-slice partials -> bf16 Q/K/Vt. grid (64 mtiles, 3 mats).
// Slice stride = 3*64*8192 floats. Fully coalesced reads and writes (V
// partials are stored [n][m]).
// ---------------------------------------------------------------------------
__global__ __launch_bounds__(256) void qkv_reduce_kernel(
    const float* __restrict__ Ppart, u16* __restrict__ Q,
    u16* __restrict__ K, u16* __restrict__ Vt)
{
  const int mtile = blockIdx.x;
  const int mat = blockIdx.y;
  const int tid = threadIdx.x;
  const size_t ksS = (size_t)3 * 64 * 8192;
  const float* base = Ppart + ((size_t)mat * 64 + mtile) * 8192;

#pragma unroll
  for (int e = 0; e < 32; e++) {
    int j = e * 256 + tid;
    float s = base[j] + base[j + ksS] + base[j + 2 * ksS] + base[j + 3 * ksS];
    if (mat < 2) {
      int m = j >> 7, n = j & 127;
      u16* out = (mat == 0) ? Q : K;
      out[(size_t)(mtile * 64 + m) * HS + n] = f2bf(s);
    } else {
      int n = j >> 6, m = j & 63;
      Vt[(size_t)n * T_TOK + mtile * 64 + m] = f2bf(s);
    }
  }
}

// ---------------------------------------------------------------------------
// Split-KV flash attention (unchanged from round 10).
// ---------------------------------------------------------------------------
__global__ __launch_bounds__(256, 2) void attn_split_kernel(
    const u16* __restrict__ Q, const u16* __restrict__ Kg,
    const u16* __restrict__ Vt, float* __restrict__ Opart,
    float* __restrict__ mstat, float* __restrict__ lstat)
{
  __shared__ __align__(16) u16 Ks[2][64 * 128];   // 2 x 16 KB
  __shared__ __align__(16) u16 Vs[2][128 * 64];   // 2 x 16 KB
  __shared__ __align__(16) u16 Ps[4 * 16 * 64];   // 8 KB (per-wave P)

  const int qtile = 63 - (int)blockIdx.x;         // heavy blocks first
  const int ch = blockIdx.y;
  if (4 * ch > qtile) return;
  const int t0 = 4 * ch;
  const int nsteps = min(CKV, qtile + 1 - t0);
  const int q0 = qtile * 64;
  const int slot = 64 * ch - 2 * ch * (ch - 1) + (qtile - 4 * ch);

  const int tid = threadIdx.x;
  const int wv = tid >> 6, lane = tid & 63, l15 = lane & 15, quad = lane >> 4;

  // Q A-frags: A[m=l15][k=quad*8+j]
  bf16x8 qf[4];
#pragma unroll
  for (int kc = 0; kc < 4; kc++)
    qf[kc] = *(const bf16x8*)(Q + (size_t)(q0 + 16 * wv + l15) * HS + kc * 32 + quad * 8);

  f32x4 o[8];
#pragma unroll
  for (int i = 0; i < 8; i++) o[i] = (f32x4)0.0f;
  float mrun[4], lrun[4];
#pragma unroll
  for (int r = 0; r < 4; r++) { mrun[r] = -1e30f; lrun[r] = 0.0f; }

  const float sc = 0.12752761571239668f; // log2(e)/sqrt(128)

  auto stage = [&](int t, int buf) {
#pragma unroll
    for (int j = 0; j < 4; j++) {
      int s = (wv * 4 + j) * 64 + lane;
      int n = s >> 4, cs = s & 15, c = cs ^ (n & 7);
      async_ld16(Kg + (size_t)(t * 64 + n) * HS + c * 8,
                 (char*)Ks[buf] + (size_t)(wv * 4 + j) * 1024);
    }
#pragma unroll
    for (int j = 0; j < 4; j++) {
      int s = (wv * 4 + j) * 64 + lane;
      int vr = s >> 3, cs = s & 7, c = cs ^ (vr & 7);
      async_ld16(Vt + (size_t)vr * T_TOK + t * 64 + c * 8,
                 (char*)Vs[buf] + (size_t)(wv * 4 + j) * 1024);
    }
  };

  stage(t0, 0);
  for (int i = 0; i < nsteps; i++) {
    const int cur = i & 1;
    const int t = t0 + i;
    __syncthreads();                           // drains loads for buf cur
    if (i + 1 < nsteps) stage(t + 1, 1 - cur); // prefetch overlaps compute

    // S = Q K^T
    f32x4 sacc[4];
#pragma unroll
    for (int nt = 0; nt < 4; nt++) sacc[nt] = (f32x4)0.0f;
#pragma unroll
    for (int kc = 0; kc < 4; kc++) {
      const int cl = kc * 4 + quad;
#pragma unroll
      for (int nt = 0; nt < 4; nt++) {
        int n = 16 * nt + l15;
        bf16x8 b = *(const bf16x8*)((const char*)Ks[cur] + (n * 16 + (cl ^ (n & 7))) * 16);
        sacc[nt] = __builtin_amdgcn_mfma_f32_16x16x32_bf16(qf[kc], b, sacc[nt], 0, 0, 0);
      }
    }

    // scale into log2 domain + causal mask (diagonal tile only)
    float s2[4][4];
    const bool diag = (t == qtile);
#pragma unroll
    for (int nt = 0; nt < 4; nt++)
#pragma unroll
      for (int r = 0; r < 4; r++) {
        float v = sacc[nt][r] * sc;
        if (diag) {
          int qr = q0 + 16 * wv + quad * 4 + r;
          int kr = t * 64 + 16 * nt + l15;
          if (kr > qr) v = -1e30f;
        }
        s2[nt][r] = v;
      }

    // online softmax; each row lives in the 16 lanes of one quad
    float mnew[4], alpha[4];
#pragma unroll
    for (int r = 0; r < 4; r++) {
      float tmax = fmaxf(fmaxf(s2[0][r], s2[1][r]), fmaxf(s2[2][r], s2[3][r]));
#pragma unroll
      for (int off = 1; off < 16; off <<= 1) tmax = fmaxf(tmax, __shfl_xor(tmax, off));
      mnew[r] = fmaxf(mrun[r], tmax);
      alpha[r] = exp2f(mrun[r] - mnew[r]);
      mrun[r] = mnew[r];
    }
    float p[4][4];
#pragma unroll
    for (int r = 0; r < 4; r++) {
      float s = 0.0f;
#pragma unroll
      for (int nt = 0; nt < 4; nt++) { p[nt][r] = exp2f(s2[nt][r] - mnew[r]); s += p[nt][r]; }
#pragma unroll
      for (int off = 1; off < 16; off <<= 1) s += __shfl_xor(s, off);
      lrun[r] = lrun[r] * alpha[r] + s;
    }
#pragma unroll
    for (int c = 0; c < 8; c++)
#pragma unroll
      for (int r = 0; r < 4; r++) o[c][r] *= alpha[r];

    // P: C-layout -> per-wave LDS (no barrier: DS in-order, Ps wave-private)
    u16* Pw = Ps + wv * 1024;
#pragma unroll
    for (int nt = 0; nt < 4; nt++)
#pragma unroll
      for (int r = 0; r < 4; r++) {
        int row = quad * 4 + r;
        int col = nt * 16 + l15;
        int cc = col >> 3, wi = col & 7;
        Pw[(row * 8 + (cc ^ (row & 7))) * 8 + wi] = f2bf(p[nt][r]);
      }

    // O += P V
#pragma unroll
    for (int kc = 0; kc < 2; kc++) {
      const int cl = kc * 4 + quad;
      bf16x8 a = *(const bf16x8*)((const char*)Pw + (l15 * 8 + (cl ^ (l15 & 7))) * 16);
#pragma unroll
      for (int c = 0; c < 8; c++) {
        int vr = 16 * c + l15;
        bf16x8 b = *(const bf16x8*)((const char*)Vs[cur] + (vr * 8 + (cl ^ (vr & 7))) * 16);
        o[c] = __builtin_amdgcn_mfma_f32_16x16x32_bf16(a, b, o[c], 0, 0, 0);
      }
    }
  }

  // store fp32 partial O + stats
  float* po = Opart + (size_t)slot * 64 * 128;
#pragma unroll
  for (int c = 0; c < 8; c++)
#pragma unroll
    for (int r = 0; r < 4; r++) {
      int ml = 16 * wv + quad * 4 + r;
      po[ml * 128 + 16 * c + l15] = o[c][r];
    }
  if (l15 == 0) {
#pragma unroll
    for (int r = 0; r < 4; r++) {
      int ml = 16 * wv + quad * 4 + r;
      mstat[slot * 64 + ml] = mrun[r];
      lstat[slot * 64 + ml] = lrun[r];
    }
  }
}

// ---------------------------------------------------------------------------
// Combine partials (unchanged from round 10).
// ---------------------------------------------------------------------------
__global__ __launch_bounds__(256) void combine_kernel(
    const float* __restrict__ Opart, const float* __restrict__ mstat,
    const float* __restrict__ lstat, void* __restrict__ out_v,
    const int* __restrict__ dflag)
{
  const int q = blockIdx.x;
  const int cb = blockIdx.y;
  const int tid = threadIdx.x;
  const int row = tid >> 2;
  const int col = cb * 32 + (tid & 3) * 8;
  const int nch = (q + 4) / 4;   // ceil((q+1)/4)
  const bool of32 = (*dflag != 0);

  float M = -1e30f;
  {
    int base = 0;
    for (int c = 0; c < nch; c++) {
      int s = base + q - 4 * c;
      M = fmaxf(M, mstat[s * 64 + row]);
      base += 64 - 4 * c;
    }
  }
  float l = 0.0f;
  float acc[8];
#pragma unroll
  for (int j = 0; j < 8; j++) acc[j] = 0.0f;
  {
    int base = 0;
    for (int c = 0; c < nch; c++) {
      int s = base + q - 4 * c;
      float w = exp2f(mstat[s * 64 + row] - M);
      l += w * lstat[s * 64 + row];
      const float* op = Opart + ((size_t)s * 64 + row) * 128 + col;
      f32x4 a = *(const f32x4*)op;
      f32x4 b = *(const f32x4*)(op + 4);
#pragma unroll
      for (int j = 0; j < 4; j++) { acc[j] += w * a[j]; acc[4 + j] += w * b[j]; }
      base += 64 - 4 * c;
    }
  }
  const float inv = 1.0f / l;
  const size_t goff = (size_t)(q * 64 + row) * HS + col;
  if (of32) {
    float* out = (float*)out_v + goff;
    f32x4 r0, r1;
#pragma unroll
    for (int j = 0; j < 4; j++) { r0[j] = acc[j] * inv; r1[j] = acc[4 + j] * inv; }
    *(f32x4*)out = r0;
    *(f32x4*)(out + 4) = r1;
  } else {
    u16* out = (u16*)out_v + goff;
    us4 r0, r1;
#pragma unroll
    for (int j = 0; j < 4; j++) { r0[j] = f2bf(acc[j] * inv); r1[j] = f2bf(acc[4 + j] * inv); }
    *(us4*)out = r0;
    *(us4*)(out + 4) = r1;
  }
}

extern "C" void kernel_launch(void* const* d_in, const int* in_sizes, int n_in,
                              void* d_out, int out_size, void* d_ws, size_t ws_size,
                              hipStream_t stream) {
  const u16* x  = (const u16*)d_in[0];
  const u16* Wq = (const u16*)d_in[1];
  const u16* Wk = (const u16*)d_in[2];
  const u16* Wv = (const u16*)d_in[3];

  // ws layout (u16 units). Region 1 (attn partials) is written only by
  // attn_split (after qkv+reduce). qkv partials live at a disjoint 32 MB
  // offset (dead after qkv_reduce).
  float* Opart = (float*)d_ws;                   // 544 * 64*128 fp32 (17.8 MB)
  float* mstat = Opart + (size_t)544 * 64 * 128;
  float* lstat = mstat + (size_t)544 * 64;

  u16* Wqb = (u16*)(lstat + (size_t)544 * 64);   // 3 x 128*2048 bf16
  u16* Wkb = Wqb + (size_t)HS * D_IN;
  u16* Wvb = Wkb + (size_t)HS * D_IN;
  u16* Q   = Wvb + (size_t)HS * D_IN;            // 4096*128 bf16 each
  u16* K   = Q   + (size_t)T_TOK * HS;
  u16* Vt  = K   + (size_t)T_TOK * HS;
  int* flag = (int*)(Vt + (size_t)T_TOK * HS);

  float* qkvP = (float*)((char*)d_ws + ((size_t)32 << 20)); // 4*3*64*8192 fp32 (25.2 MB)

  conv3_kernel<<<384, 256, 0, stream>>>(Wq, Wk, Wv, Wqb, Wkb, Wvb, flag);
  qkv_kernel<<<dim3(64, 3, 4), 256, 0, stream>>>(x, Wqb, Wkb, Wvb, qkvP);
  qkv_reduce_kernel<<<dim3(64, 3), 256, 0, stream>>>(qkvP, Q, K, Vt);
  attn_split_kernel<<<dim3(64, NCH), 256, 0, stream>>>(Q, K, Vt, Opart, mstat, lstat);
  combine_kernel<<<dim3(64, 4), 256, 0, stream>>>(Opart, mstat, lstat, d_out, flag);
}